// Round 2
// baseline (6463.896 us; speedup 1.0000x reference)
//
#include <hip/hip_runtime.h>
#include <hip/hip_bf16.h>

// Doubly-recurrent LSTM + gumbel-sigmoid gate, B=256,T=64,H=512,V=6207,YF=2048.
// Inputs/outputs are FP32 (per reference dtypes). MFMA path uses split-bf16
// (hi+lo) for BOTH operands, 3-pass (AhBh + AhBl + AlBh), fp32 accumulators ->
// fp32-faithful so the hard gate (y_soft >= 0.5) matches the numpy reference.

typedef __attribute__((ext_vector_type(8))) short short8;   // 8 bf16 = 1 MFMA operand
typedef __attribute__((ext_vector_type(4))) float floatx4;  // MFMA accumulator

#define MFMA16(a, b, c) __builtin_amdgcn_mfma_f32_16x16x32_bf16(a, b, c, 0, 0, 0)

__device__ inline float bf2f(ushort u) {
    union { unsigned int u32; float f; } v; v.u32 = ((unsigned int)u) << 16; return v.f;
}
__device__ inline ushort f2bf(float f) {  // round-to-nearest-even (finite inputs only)
    union { float f; unsigned int u; } v; v.f = f;
    return (ushort)((v.u + 0x7fffu + ((v.u >> 16) & 1u)) >> 16);
}
__device__ inline short8 ld8(const ushort* p) { return *(const short8*)p; }
__device__ inline float sigf(float x) { return 1.0f / (1.0f + expf(-x)); }
__device__ inline void mm3(floatx4& acc, short8 ah, short8 al, short8 bh, short8 bl) {
    acc = MFMA16(ah, bh, acc);
    acc = MFMA16(ah, bl, acc);
    acc = MFMA16(al, bh, acc);
}

// ---------------------------------------------------------------------------
// prep: split fp32 arrays into bf16 hi/lo pairs in ws.
// Segments (elems): W_ih,W_hh,W_ih_t,W_hh_t (1048576 ea), Wg 1310720,
// Wlin 131072, emb 3177984, y 524288. Total 9338368.
// ---------------------------------------------------------------------------
__global__ __launch_bounds__(256) void k_prep(const float* __restrict__ w0,
                                              const float* __restrict__ w1,
                                              const float* __restrict__ w2,
                                              const float* __restrict__ w3,
                                              const float* __restrict__ wg,
                                              const float* __restrict__ wl,
                                              const float* __restrict__ em,
                                              const float* __restrict__ yy,
                                              ushort* __restrict__ wreg) {
    unsigned i = blockIdx.x * 256u + threadIdx.x;
    if (i >= 9338368u) return;
    const float* src; ushort* hi; unsigned n, loc;
    if (i < 4194304u) {
        unsigned seg = i >> 20; loc = i & 1048575u; n = 1048576u;
        hi = wreg + seg * 2097152u;
        src = (seg == 0) ? w0 : (seg == 1) ? w1 : (seg == 2) ? w2 : w3;
    } else if (i < 5505024u) { loc = i - 4194304u; src = wg; hi = wreg + 8388608u;  n = 1310720u; }
    else if (i < 5636096u)   { loc = i - 5505024u; src = wl; hi = wreg + 11010048u; n = 131072u; }
    else if (i < 8814080u)   { loc = i - 5636096u; src = em; hi = wreg + 11272192u; n = 3177984u; }
    else                     { loc = i - 8814080u; src = yy; hi = wreg + 17628160u; n = 524288u; }
    float v = src[loc];
    ushort h = f2bf(v);
    hi[loc] = h;
    hi[n + loc] = f2bf(v - bf2f(h));
}

// ---------------------------------------------------------------------------
// gy = y @ Wg[:,512:].T + bg     (M=256, N=512, K=2048) -> fp32
// ---------------------------------------------------------------------------
__global__ __launch_bounds__(256) void k_gy(const ushort* __restrict__ y_hi,
                                            const ushort* __restrict__ y_lo,
                                            const ushort* __restrict__ Wg_hi,
                                            const ushort* __restrict__ Wg_lo,
                                            const float* __restrict__ bg,
                                            float* __restrict__ gy) {
    int tid = threadIdx.x, lane = tid & 63, w = tid >> 6;
    int wm = w & 1, wn = w >> 1, quad = lane >> 4, lr = lane & 15;
    int m0 = blockIdx.y * 64, n0 = blockIdx.x * 64;
    floatx4 acc[2][2] = {};
    for (int k0 = 0; k0 < 2048; k0 += 32) {
        short8 ah[2], al[2], bh[2], bl[2];
#pragma unroll
        for (int tm = 0; tm < 2; tm++) {
            int r = m0 + wm * 32 + tm * 16 + lr;
            ah[tm] = ld8(y_hi + r * 2048 + k0 + quad * 8);
            al[tm] = ld8(y_lo + r * 2048 + k0 + quad * 8);
        }
#pragma unroll
        for (int tn = 0; tn < 2; tn++) {
            int n = n0 + wn * 32 + tn * 16 + lr;
            bh[tn] = ld8(Wg_hi + n * 2560 + 512 + k0 + quad * 8);
            bl[tn] = ld8(Wg_lo + n * 2560 + 512 + k0 + quad * 8);
        }
#pragma unroll
        for (int tm = 0; tm < 2; tm++)
#pragma unroll
            for (int tn = 0; tn < 2; tn++) mm3(acc[tm][tn], ah[tm], al[tm], bh[tn], bl[tn]);
    }
#pragma unroll
    for (int tm = 0; tm < 2; tm++)
#pragma unroll
        for (int tn = 0; tn < 2; tn++)
#pragma unroll
            for (int r4 = 0; r4 < 4; r4++) {
                int row = m0 + wm * 32 + tm * 16 + quad * 4 + r4;
                int n = n0 + wn * 32 + tn * 16 + lr;
                gy[row * 512 + n] = acc[tm][tn][r4] + bg[n];
            }
}

// ---------------------------------------------------------------------------
// S1: z = h@W_hh.T + emb[x_t]@W_ih.T + b_ih + b_hh ; LSTM update -> h (hi/lo), c
// Block covers 64 rows x 16 h-cols (all 4 gate slices). h double-buffered.
// ---------------------------------------------------------------------------
__global__ __launch_bounds__(256) void k_s1(const ushort* __restrict__ h_in,
                                            ushort* __restrict__ h_out,
                                            const int* __restrict__ x,
                                            const ushort* __restrict__ emb_hi,
                                            const ushort* __restrict__ emb_lo,
                                            const ushort* __restrict__ Whh_hi,
                                            const ushort* __restrict__ Whh_lo,
                                            const ushort* __restrict__ Wih_hi,
                                            const ushort* __restrict__ Wih_lo,
                                            const float* __restrict__ b_ih,
                                            const float* __restrict__ b_hh,
                                            float* __restrict__ c, int t) {
    __shared__ float zs[64][68];
    int tid = threadIdx.x, lane = tid & 63, w = tid >> 6;
    int wm = w & 1, wn = w >> 1, quad = lane >> 4, lr = lane & 15;
    int m0 = blockIdx.y * 64, j0 = blockIdx.x * 16;
    int r[2], n[2];
#pragma unroll
    for (int tm = 0; tm < 2; tm++) r[tm] = m0 + wm * 32 + tm * 16 + lr;
#pragma unroll
    for (int tg = 0; tg < 2; tg++) n[tg] = (wn * 2 + tg) * 512 + j0 + lr;

    floatx4 acc[2][2] = {};
    // h (hi+lo) @ W_hh.T (hi+lo)
    for (int k0 = 0; k0 < 512; k0 += 32) {
        short8 ah[2], al[2], bh[2], bl[2];
#pragma unroll
        for (int tg = 0; tg < 2; tg++) {
            bh[tg] = ld8(Whh_hi + n[tg] * 512 + k0 + quad * 8);
            bl[tg] = ld8(Whh_lo + n[tg] * 512 + k0 + quad * 8);
        }
#pragma unroll
        for (int tm = 0; tm < 2; tm++) {
            ah[tm] = ld8(h_in + r[tm] * 1024 + k0 + quad * 8);
            al[tm] = ld8(h_in + r[tm] * 1024 + 512 + k0 + quad * 8);
        }
#pragma unroll
        for (int tm = 0; tm < 2; tm++)
#pragma unroll
            for (int tg = 0; tg < 2; tg++) mm3(acc[tm][tg], ah[tm], al[tm], bh[tg], bl[tg]);
    }
    // emb[x[:,t]] (hi+lo) @ W_ih.T (hi+lo)
    int tok[2];
#pragma unroll
    for (int tm = 0; tm < 2; tm++) tok[tm] = x[r[tm] * 64 + t];
    for (int k0 = 0; k0 < 512; k0 += 32) {
        short8 ah[2], al[2], bh[2], bl[2];
#pragma unroll
        for (int tg = 0; tg < 2; tg++) {
            bh[tg] = ld8(Wih_hi + n[tg] * 512 + k0 + quad * 8);
            bl[tg] = ld8(Wih_lo + n[tg] * 512 + k0 + quad * 8);
        }
#pragma unroll
        for (int tm = 0; tm < 2; tm++) {
            ah[tm] = ld8(emb_hi + tok[tm] * 512 + k0 + quad * 8);
            al[tm] = ld8(emb_lo + tok[tm] * 512 + k0 + quad * 8);
        }
#pragma unroll
        for (int tm = 0; tm < 2; tm++)
#pragma unroll
            for (int tg = 0; tg < 2; tg++) mm3(acc[tm][tg], ah[tm], al[tm], bh[tg], bl[tg]);
    }
    // stage z (+biases) to LDS: layout [m_local][gate*16 + j_local]
#pragma unroll
    for (int tm = 0; tm < 2; tm++)
#pragma unroll
        for (int tg = 0; tg < 2; tg++) {
            float bias = b_ih[n[tg]] + b_hh[n[tg]];
#pragma unroll
            for (int r4 = 0; r4 < 4; r4++)
                zs[wm * 32 + tm * 16 + quad * 4 + r4][(wn * 2 + tg) * 16 + lr] =
                    acc[tm][tg][r4] + bias;
        }
    __syncthreads();
#pragma unroll
    for (int e = 0; e < 4; e++) {
        int idx = e * 256 + tid, ml = idx >> 4, jj = idx & 15;
        float zi = zs[ml][jj], zf = zs[ml][16 + jj], zg = zs[ml][32 + jj], zo = zs[ml][48 + jj];
        int gidx = (m0 + ml) * 512 + j0 + jj;
        float cv = c[gidx];
        cv = sigf(zf) * cv + sigf(zi) * tanhf(zg);
        c[gidx] = cv;
        float h = sigf(zo) * tanhf(cv);
        ushort hi = f2bf(h);
        ushort lo = f2bf(h - bf2f(hi));
        h_out[(m0 + ml) * 1024 + j0 + jj] = hi;
        h_out[(m0 + ml) * 1024 + 512 + j0 + jj] = lo;
    }
}

// ---------------------------------------------------------------------------
// S2: logits = relu(h@Wg[:,:512].T + gy); gumbel-sigmoid hard gate; hf = h*gate
// gate is exactly 0/1 so hf hi/lo = masked h hi/lo (exact split preserved).
// ---------------------------------------------------------------------------
__global__ __launch_bounds__(256) void k_s2(const ushort* __restrict__ h_in,
                                            const ushort* __restrict__ Wg_hi,
                                            const ushort* __restrict__ Wg_lo,
                                            const float* __restrict__ gy,
                                            const float* __restrict__ u1,
                                            const float* __restrict__ u2,
                                            ushort* __restrict__ hf, int t) {
    int tid = threadIdx.x, lane = tid & 63, w = tid >> 6;
    int wm = w & 1, wn = w >> 1, quad = lane >> 4, lr = lane & 15;
    int m0 = blockIdx.y * 64, n0 = blockIdx.x * 64;
    floatx4 acc[2][2] = {};
    for (int k0 = 0; k0 < 512; k0 += 32) {
        short8 ah[2], al[2], bh[2], bl[2];
#pragma unroll
        for (int tn = 0; tn < 2; tn++) {
            int n = n0 + wn * 32 + tn * 16 + lr;
            bh[tn] = ld8(Wg_hi + n * 2560 + k0 + quad * 8);
            bl[tn] = ld8(Wg_lo + n * 2560 + k0 + quad * 8);
        }
#pragma unroll
        for (int tm = 0; tm < 2; tm++) {
            int r = m0 + wm * 32 + tm * 16 + lr;
            ah[tm] = ld8(h_in + r * 1024 + k0 + quad * 8);
            al[tm] = ld8(h_in + r * 1024 + 512 + k0 + quad * 8);
        }
#pragma unroll
        for (int tm = 0; tm < 2; tm++)
#pragma unroll
            for (int tn = 0; tn < 2; tn++) mm3(acc[tm][tn], ah[tm], al[tm], bh[tn], bl[tn]);
    }
    const float EPS = 1e-10f;
#pragma unroll
    for (int tm = 0; tm < 2; tm++)
#pragma unroll
        for (int tn = 0; tn < 2; tn++)
#pragma unroll
            for (int r4 = 0; r4 < 4; r4++) {
                int row = m0 + wm * 32 + tm * 16 + quad * 4 + r4;
                int j = n0 + wn * 32 + tn * 16 + lr;
                float logit = acc[tm][tn][r4] + gy[row * 512 + j];
                logit = fmaxf(logit, 0.0f);
                float U1 = u1[t * 131072 + row * 512 + j];
                float U2 = u2[t * 131072 + row * 512 + j];
                float noise = -logf(logf(U2 + EPS) / logf(U1 + EPS) + EPS);
                float ys = sigf(logit + noise);
                bool gbit = (ys >= 0.5f);
                hf[row * 1024 + j] = gbit ? h_in[row * 1024 + j] : (ushort)0;
                hf[row * 1024 + 512 + j] = gbit ? h_in[row * 1024 + 512 + j] : (ushort)0;
            }
}

// ---------------------------------------------------------------------------
// S3: z = hf@W_ih_t.T + ht@W_hh_t.T + b_ih_t + b_hh_t ; LSTM -> ht (hi/lo), ct
// ht double-buffered (other blocks may still be reading ht_in).
// ---------------------------------------------------------------------------
__global__ __launch_bounds__(256) void k_s3(const ushort* __restrict__ hf,
                                            const ushort* __restrict__ ht_in,
                                            ushort* __restrict__ ht_out,
                                            const ushort* __restrict__ Wiht_hi,
                                            const ushort* __restrict__ Wiht_lo,
                                            const ushort* __restrict__ Whht_hi,
                                            const ushort* __restrict__ Whht_lo,
                                            const float* __restrict__ b_ih_t,
                                            const float* __restrict__ b_hh_t,
                                            float* __restrict__ ct) {
    __shared__ float zs[64][68];
    int tid = threadIdx.x, lane = tid & 63, w = tid >> 6;
    int wm = w & 1, wn = w >> 1, quad = lane >> 4, lr = lane & 15;
    int m0 = blockIdx.y * 64, j0 = blockIdx.x * 16;
    int r[2], n[2];
#pragma unroll
    for (int tm = 0; tm < 2; tm++) r[tm] = m0 + wm * 32 + tm * 16 + lr;
#pragma unroll
    for (int tg = 0; tg < 2; tg++) n[tg] = (wn * 2 + tg) * 512 + j0 + lr;

    floatx4 acc[2][2] = {};
    // hf (hi+lo) @ W_ih_t.T (hi+lo)
    for (int k0 = 0; k0 < 512; k0 += 32) {
        short8 ah[2], al[2], bh[2], bl[2];
#pragma unroll
        for (int tg = 0; tg < 2; tg++) {
            bh[tg] = ld8(Wiht_hi + n[tg] * 512 + k0 + quad * 8);
            bl[tg] = ld8(Wiht_lo + n[tg] * 512 + k0 + quad * 8);
        }
#pragma unroll
        for (int tm = 0; tm < 2; tm++) {
            ah[tm] = ld8(hf + r[tm] * 1024 + k0 + quad * 8);
            al[tm] = ld8(hf + r[tm] * 1024 + 512 + k0 + quad * 8);
        }
#pragma unroll
        for (int tm = 0; tm < 2; tm++)
#pragma unroll
            for (int tg = 0; tg < 2; tg++) mm3(acc[tm][tg], ah[tm], al[tm], bh[tg], bl[tg]);
    }
    // ht (hi+lo) @ W_hh_t.T (hi+lo)
    for (int k0 = 0; k0 < 512; k0 += 32) {
        short8 ah[2], al[2], bh[2], bl[2];
#pragma unroll
        for (int tg = 0; tg < 2; tg++) {
            bh[tg] = ld8(Whht_hi + n[tg] * 512 + k0 + quad * 8);
            bl[tg] = ld8(Whht_lo + n[tg] * 512 + k0 + quad * 8);
        }
#pragma unroll
        for (int tm = 0; tm < 2; tm++) {
            ah[tm] = ld8(ht_in + r[tm] * 1024 + k0 + quad * 8);
            al[tm] = ld8(ht_in + r[tm] * 1024 + 512 + k0 + quad * 8);
        }
#pragma unroll
        for (int tm = 0; tm < 2; tm++)
#pragma unroll
            for (int tg = 0; tg < 2; tg++) mm3(acc[tm][tg], ah[tm], al[tm], bh[tg], bl[tg]);
    }
#pragma unroll
    for (int tm = 0; tm < 2; tm++)
#pragma unroll
        for (int tg = 0; tg < 2; tg++) {
            float bias = b_ih_t[n[tg]] + b_hh_t[n[tg]];
#pragma unroll
            for (int r4 = 0; r4 < 4; r4++)
                zs[wm * 32 + tm * 16 + quad * 4 + r4][(wn * 2 + tg) * 16 + lr] =
                    acc[tm][tg][r4] + bias;
        }
    __syncthreads();
#pragma unroll
    for (int e = 0; e < 4; e++) {
        int idx = e * 256 + tid, ml = idx >> 4, jj = idx & 15;
        float zi = zs[ml][jj], zf = zs[ml][16 + jj], zg = zs[ml][32 + jj], zo = zs[ml][48 + jj];
        int gidx = (m0 + ml) * 512 + j0 + jj;
        float cv = ct[gidx];
        cv = sigf(zf) * cv + sigf(zi) * tanhf(zg);
        ct[gidx] = cv;
        float h = sigf(zo) * tanhf(cv);
        ushort hi = f2bf(h);
        ushort lo = f2bf(h - bf2f(hi));
        ht_out[(m0 + ml) * 1024 + j0 + jj] = hi;
        ht_out[(m0 + ml) * 1024 + 512 + j0 + jj] = lo;
    }
}

// ---------------------------------------------------------------------------
// out = relu(ht @ Wlin.T + blin)  (M=256, N=256, K=512 hi/lo) -> fp32
// ---------------------------------------------------------------------------
__global__ __launch_bounds__(256) void k_final(const ushort* __restrict__ ht,
                                               const ushort* __restrict__ Wl_hi,
                                               const ushort* __restrict__ Wl_lo,
                                               const float* __restrict__ blin,
                                               float* __restrict__ out) {
    int tid = threadIdx.x, lane = tid & 63, w = tid >> 6;
    int wm = w & 1, wn = w >> 1, quad = lane >> 4, lr = lane & 15;
    int m0 = blockIdx.y * 64, n0 = blockIdx.x * 64;
    floatx4 acc[2][2] = {};
    for (int k0 = 0; k0 < 512; k0 += 32) {
        short8 ah[2], al[2], bh[2], bl[2];
#pragma unroll
        for (int tn = 0; tn < 2; tn++) {
            int n = n0 + wn * 32 + tn * 16 + lr;
            bh[tn] = ld8(Wl_hi + n * 512 + k0 + quad * 8);
            bl[tn] = ld8(Wl_lo + n * 512 + k0 + quad * 8);
        }
#pragma unroll
        for (int tm = 0; tm < 2; tm++) {
            int r = m0 + wm * 32 + tm * 16 + lr;
            ah[tm] = ld8(ht + r * 1024 + k0 + quad * 8);
            al[tm] = ld8(ht + r * 1024 + 512 + k0 + quad * 8);
        }
#pragma unroll
        for (int tm = 0; tm < 2; tm++)
#pragma unroll
            for (int tn = 0; tn < 2; tn++) mm3(acc[tm][tn], ah[tm], al[tm], bh[tn], bl[tn]);
    }
#pragma unroll
    for (int tm = 0; tm < 2; tm++)
#pragma unroll
        for (int tn = 0; tn < 2; tn++)
#pragma unroll
            for (int r4 = 0; r4 < 4; r4++) {
                int row = m0 + wm * 32 + tm * 16 + quad * 4 + r4;
                int n = n0 + wn * 32 + tn * 16 + lr;
                out[row * 256 + n] = fmaxf(acc[tm][tn][r4] + blin[n], 0.0f);
            }
}

// ---------------------------------------------------------------------------
extern "C" void kernel_launch(void* const* d_in, const int* in_sizes, int n_in,
                              void* d_out, int out_size, void* d_ws, size_t ws_size,
                              hipStream_t stream) {
    (void)in_sizes; (void)n_in; (void)out_size; (void)ws_size;
    const float* y      = (const float*)d_in[0];
    const int*   x      = (const int*)d_in[1];
    const float* emb    = (const float*)d_in[2];
    const float* W_ih   = (const float*)d_in[3];
    const float* W_hh   = (const float*)d_in[4];
    const float* b_ih   = (const float*)d_in[5];
    const float* b_hh   = (const float*)d_in[6];
    const float* W_ih_t = (const float*)d_in[7];
    const float* W_hh_t = (const float*)d_in[8];
    const float* b_ih_t = (const float*)d_in[9];
    const float* b_hh_t = (const float*)d_in[10];
    const float* Wg     = (const float*)d_in[11];
    const float* bg     = (const float*)d_in[12];
    const float* Wlin   = (const float*)d_in[13];
    const float* blin   = (const float*)d_in[14];
    const float* u1     = (const float*)d_in[15];
    const float* u2     = (const float*)d_in[16];
    float* out = (float*)d_out;

    // ws layout: [c|ct|gy fp32][h0|ht0|h1|ht1|hf bf16 hi|lo][weight hi/lo region]
    float*  wsf = (float*)d_ws;
    float*  c   = wsf;                 // 131072 f32
    float*  ct  = wsf + 131072;        // 131072 f32
    float*  gy  = wsf + 262144;        // 131072 f32
    ushort* s   = (ushort*)(wsf + 393216);
    ushort* h0  = s;                   // 262144 each (512 hi | 512 lo per row)
    ushort* ht0 = s + 262144;
    ushort* h1  = s + 524288;
    ushort* ht1 = s + 786432;
    ushort* hfb = s + 1048576;
    ushort* wreg = s + 1310720;
    const ushort* Wih_hi  = wreg;             const ushort* Wih_lo  = wreg + 1048576;
    const ushort* Whh_hi  = wreg + 2097152;   const ushort* Whh_lo  = wreg + 3145728;
    const ushort* Wiht_hi = wreg + 4194304;   const ushort* Wiht_lo = wreg + 5242880;
    const ushort* Whht_hi = wreg + 6291456;   const ushort* Whht_lo = wreg + 7340032;
    const ushort* Wg_hi   = wreg + 8388608;   const ushort* Wg_lo   = wreg + 9699328;
    const ushort* Wl_hi   = wreg + 11010048;  const ushort* Wl_lo   = wreg + 11141120;
    const ushort* em_hi   = wreg + 11272192;  const ushort* em_lo   = wreg + 14450176;
    const ushort* y_hi    = wreg + 17628160;  const ushort* y_lo    = wreg + 18152448;

    // zero c, ct, gy, h0, ht0 (gy zeroing harmless; keeps range contiguous)
    hipMemsetAsync(d_ws, 0, 2621440, stream);

    dim3 blk(256);
    k_prep<<<dim3(36478), blk, 0, stream>>>(W_ih, W_hh, W_ih_t, W_hh_t, Wg, Wlin, emb, y,
                                            (ushort*)wreg);
    k_gy<<<dim3(8, 4), blk, 0, stream>>>(y_hi, y_lo, Wg_hi, Wg_lo, bg, gy);
    for (int t = 0; t < 64; t++) {
        ushort* hA  = (t & 1) ? h1 : h0;
        ushort* hB  = (t & 1) ? h0 : h1;
        ushort* htA = (t & 1) ? ht1 : ht0;
        ushort* htB = (t & 1) ? ht0 : ht1;
        k_s1<<<dim3(32, 4), blk, 0, stream>>>(hA, hB, x, em_hi, em_lo, Whh_hi, Whh_lo,
                                              Wih_hi, Wih_lo, b_ih, b_hh, c, t);
        k_s2<<<dim3(8, 4), blk, 0, stream>>>(hB, Wg_hi, Wg_lo, gy, u1, u2, hfb, t);
        k_s3<<<dim3(32, 4), blk, 0, stream>>>(hfb, htA, htB, Wiht_hi, Wiht_lo,
                                              Whht_hi, Whht_lo, b_ih_t, b_hh_t, ct);
    }
    // after t=63 (odd) the final ht lives in ht0
    k_final<<<dim3(4, 4), blk, 0, stream>>>(ht0, Wl_hi, Wl_lo, blin, out);
}